// Round 9
// baseline (197.776 us; speedup 1.0000x reference)
//
#include <hip/hip_runtime.h>
#include <stdint.h>

typedef unsigned short u16;
typedef unsigned int u32;
typedef __attribute__((ext_vector_type(8))) short short8;
typedef __attribute__((ext_vector_type(4))) float float4v;

#define Bb 4
#define Ss 256
#define Hh 768
#define NALL 64
#define GRID 512          // 2 blocks/CU: co-residency guaranteed (18.4KB LDS, ~64 VGPR)
#define MAGIC 0x1234ABCD

// Inputs/outputs are FP32 (reference dtype; established r7).

__device__ __forceinline__ float b2f(u16 h) {
    u32 u = ((u32)h) << 16;
    float f;
    __builtin_memcpy(&f, &u, 4);
    return f;
}
__device__ __forceinline__ u16 f2b(float f) {
    u32 u;
    __builtin_memcpy(&u, &f, 4);
    u = (u + 0x7fffu + ((u >> 16) & 1u)) >> 16;  // RNE
    return (u16)u;
}

// Grid barrier over poisoned ws. r4 lesson: NEVER poll with acquire on CDNA4
// (every acquire atomic = whole-L2 invalidate -> ~90us/barrier). Here: polls
// are RELAXED (no inv), arrival is one RELEASE fetch_add (one wbl2), and a
// single acquire fence per block after poll exit publishes the phase.
__device__ __forceinline__ void gbar(int* bar, int idx) {
    __syncthreads();
    if (threadIdx.x == 0) {
        while (__hip_atomic_load(&bar[0], __ATOMIC_RELAXED, __HIP_MEMORY_SCOPE_AGENT) != MAGIC)
            __builtin_amdgcn_s_sleep(1);
        __hip_atomic_fetch_add(&bar[1 + idx], 1, __ATOMIC_RELEASE, __HIP_MEMORY_SCOPE_AGENT);
        while (__hip_atomic_load(&bar[1 + idx], __ATOMIC_RELAXED, __HIP_MEMORY_SCOPE_AGENT) < GRID)
            __builtin_amdgcn_s_sleep(2);
        __builtin_amdgcn_fence(__ATOMIC_ACQUIRE, "agent");  // one L2 inv per block
    }
    __syncthreads();
}

__global__ __launch_bounds__(256, 2) void k_fused(const float* __restrict__ h,
                                                  const int* __restrict__ rels,
                                                  const float* __restrict__ basic,
                                                  const float* __restrict__ relw,
                                                  const float* __restrict__ selfw,
                                                  u16* __restrict__ basicT,
                                                  u16* __restrict__ coefC,
                                                  u16* __restrict__ hbf,
                                                  u16* __restrict__ swbf,
                                                  u16* __restrict__ Gt,
                                                  int* __restrict__ bar,
                                                  float* __restrict__ out) {
    __shared__ __align__(16) u16 As[64 * 72];
    __shared__ __align__(16) u16 Bs[64 * 72];
    const int t = threadIdx.x;
    const int row = t >> 2, kk = (t & 3) * 16;
    const int w = t >> 6, l = t & 63, quad = l >> 4, l16 = l & 15;

    if (blockIdx.x == 0 && t == 0) {
        __hip_atomic_store(&bar[1], 0, __ATOMIC_RELAXED, __HIP_MEMORY_SCOPE_AGENT);
        __hip_atomic_store(&bar[2], 0, __ATOMIC_RELAXED, __HIP_MEMORY_SCOPE_AGENT);
        __hip_atomic_store(&bar[0], MAGIC, __ATOMIC_RELEASE, __HIP_MEMORY_SCOPE_AGENT);
    }

    // -------- phase A (3072 units, 6/block): basicT transpose + hbf cvt --------
    {
        u16(*tile)[34] = (u16(*)[34])As;  // 32x34 pad: conflict-free transposed read
        for (int u = blockIdx.x; u < 3072; u += GRID) {
            __syncthreads();  // protect LDS reuse across units
            if (u < 2304) {   // basicT[q][o][i] = bf16(basic[q][i][o])
                const int q = u / 576, rem = u % 576;
                const int i0 = (rem % 24) * 32, o0 = (rem / 24) * 32;
                const int tx = t & 31, ty = t >> 5;
                const size_t base = (size_t)q * Hh * Hh;
#pragma unroll
                for (int r = 0; r < 4; ++r)
                    tile[ty + 8 * r][tx] =
                        f2b(basic[base + (size_t)(i0 + ty + 8 * r) * Hh + o0 + tx]);
                __syncthreads();
#pragma unroll
                for (int r = 0; r < 4; ++r)
                    basicT[base + (size_t)(o0 + ty + 8 * r) * Hh + i0 + tx] = tile[tx][ty + 8 * r];
            } else {          // hbf cvt: 768 units x 1024 elems
                const size_t i = ((size_t)(u - 2304) * 256 + t) * 4;
                const float4 v = *(const float4*)(h + i);
                u32 lo = (u32)f2b(v.x) | ((u32)f2b(v.y) << 16);
                u32 hi = (u32)f2b(v.z) | ((u32)f2b(v.w) << 16);
                *(uint2*)(hbf + i) = make_uint2(lo, hi);
            }
        }
    }
    gbar(bar, 0);

    // -------- phase B (2368 units): Gt GEMM | coefC build | swbf cvt --------
    for (int u = blockIdx.x; u < 2368; u += GRID) {
        if (u < 768) {
            // Gt[bk][o][j] = sum_i basicT[q][o][i] * hbf[b][j][i]; K=768
            const int o0 = (u % 12) * 64, j0 = ((u / 12) % 4) * 64, bk = u / 48;
            const int b = bk >> 2, q = bk & 3;
            const u16* aB = basicT + ((size_t)q * Hh + o0 + row) * Hh + kk;
            const u16* bB = hbf + ((size_t)b * Ss + j0 + row) * Hh + kk;
            float4v acc[4];
#pragma unroll
            for (int c = 0; c < 4; ++c) acc[c] = (float4v){0.f, 0.f, 0.f, 0.f};
            uint4 a0 = *(const uint4*)aB, a1 = *(const uint4*)(aB + 8);
            uint4 b0 = *(const uint4*)bB, b1 = *(const uint4*)(bB + 8);
            for (int s = 0; s < 12; ++s) {
                __syncthreads();
                *(uint4*)(&As[row * 72 + kk]) = a0;
                *(uint4*)(&As[row * 72 + kk + 8]) = a1;
                *(uint4*)(&Bs[row * 72 + kk]) = b0;
                *(uint4*)(&Bs[row * 72 + kk + 8]) = b1;
                __syncthreads();
                if (s + 1 < 12) {
                    a0 = *(const uint4*)(aB + (s + 1) * 64);
                    a1 = *(const uint4*)(aB + (s + 1) * 64 + 8);
                    b0 = *(const uint4*)(bB + (s + 1) * 64);
                    b1 = *(const uint4*)(bB + (s + 1) * 64 + 8);
                }
#pragma unroll
                for (int k2 = 0; k2 < 64; k2 += 32) {
                    const short8 af = *(const short8*)(&As[(16 * w + l16) * 72 + k2 + quad * 8]);
#pragma unroll
                    for (int c = 0; c < 4; ++c) {
                        const short8 bfr = *(const short8*)(&Bs[(16 * c + l16) * 72 + k2 + quad * 8]);
                        acc[c] = __builtin_amdgcn_mfma_f32_16x16x32_bf16(af, bfr, acc[c], 0, 0, 0);
                    }
                }
            }
#pragma unroll
            for (int c = 0; c < 4; ++c)
#pragma unroll
                for (int r = 0; r < 4; ++r) {
                    const int ol = 16 * w + quad * 4 + r;   // D row = m = o_local
                    const int jl = 16 * c + l16;            // D col = n = j_local
                    Gt[((size_t)bk * Hh + o0 + ol) * Ss + j0 + jl] = f2b(acc[c][r]);
                }
        } else if (u < 1792) {
            // coefC build: one unit per (b,i)
            float* srelw = (float*)As;
            u32* hist = (u32*)Bs;
            const int r = u - 768;
            const int i = r & 255, b = r >> 8;
            __syncthreads();  // protect As/Bs from prior unit's reads
            srelw[t] = relw[t];
            if (t < NALL) hist[t] = 0u;
            __syncthreads();
            const int rfw = rels[(b * Ss + i) * Ss + t];
            const int rcl = rels[(b * Ss + t) * Ss + i];
            if (rfw > 0) atomicAdd(&hist[rfw], 1u);
            if (rcl > 0) atomicAdd(&hist[rcl + 32], 1u);
            __syncthreads();
            float c0 = 0.f, c1 = 0.f, c2 = 0.f, c3 = 0.f;
            if (rfw > 0) {
                const float inv = 1.0f / (float)hist[rfw];
                c0 += srelw[rfw * 4 + 0] * inv; c1 += srelw[rfw * 4 + 1] * inv;
                c2 += srelw[rfw * 4 + 2] * inv; c3 += srelw[rfw * 4 + 3] * inv;
            }
            if (rcl > 0) {
                const int rr = rcl + 32;
                const float inv = 1.0f / (float)hist[rr];
                c0 += srelw[rr * 4 + 0] * inv; c1 += srelw[rr * 4 + 1] * inv;
                c2 += srelw[rr * 4 + 2] * inv; c3 += srelw[rr * 4 + 3] * inv;
            }
            const size_t base = ((size_t)(b * 4) * Ss + i) * Ss + t;
            coefC[base] = f2b(c0);
            coefC[base + (size_t)Ss * Ss] = f2b(c1);
            coefC[base + (size_t)2 * Ss * Ss] = f2b(c2);
            coefC[base + (size_t)3 * Ss * Ss] = f2b(c3);
        } else {
            // swbf cvt: 576 units x 1024 elems
            const size_t i = ((size_t)(u - 1792) * 256 + t) * 4;
            const float4 v = *(const float4*)(selfw + i);
            u32 lo = (u32)f2b(v.x) | ((u32)f2b(v.y) << 16);
            u32 hi = (u32)f2b(v.z) | ((u32)f2b(v.w) << 16);
            *(uint2*)(swbf + i) = make_uint2(lo, hi);
        }
    }
    gbar(bar, 1);

    // -------- phase C (192 units): out = coefC@Gt (K=1024) ⊕ hbf@swbf^T (K=768) --------
    if (blockIdx.x < 192) {
        const int z = blockIdx.x;
        const int ot = z % 12, it = (z / 12) % 4, b = z / 48;
        auto aa = [&](int s) -> const u16* {
            if (s < 16)
                return coefC + ((size_t)(b * 4 + (s >> 2)) * Ss + it * 64 + row) * Ss + (s & 3) * 64 + kk;
            return hbf + ((size_t)b * Ss + it * 64 + row) * Hh + (s - 16) * 64 + kk;
        };
        auto bb = [&](int s) -> const u16* {
            if (s < 16)
                return Gt + ((size_t)(b * 4 + (s >> 2)) * Hh + ot * 64 + row) * Ss + (s & 3) * 64 + kk;
            return swbf + (size_t)(ot * 64 + row) * Hh + (s - 16) * 64 + kk;
        };
        float4v acc[4];
#pragma unroll
        for (int c = 0; c < 4; ++c) acc[c] = (float4v){0.f, 0.f, 0.f, 0.f};
        uint4 a0 = *(const uint4*)aa(0);
        uint4 a1 = *(const uint4*)(aa(0) + 8);
        uint4 b0 = *(const uint4*)bb(0);
        uint4 b1 = *(const uint4*)(bb(0) + 8);
        for (int s = 0; s < 28; ++s) {
            __syncthreads();
            *(uint4*)(&As[row * 72 + kk]) = a0;
            *(uint4*)(&As[row * 72 + kk + 8]) = a1;
            *(uint4*)(&Bs[row * 72 + kk]) = b0;
            *(uint4*)(&Bs[row * 72 + kk + 8]) = b1;
            __syncthreads();
            if (s + 1 < 28) {
                const u16* ap = aa(s + 1);
                const u16* bp = bb(s + 1);
                a0 = *(const uint4*)ap;
                a1 = *(const uint4*)(ap + 8);
                b0 = *(const uint4*)bp;
                b1 = *(const uint4*)(bp + 8);
            }
#pragma unroll
            for (int k2 = 0; k2 < 64; k2 += 32) {
                const short8 af = *(const short8*)(&As[(16 * w + l16) * 72 + k2 + quad * 8]);
#pragma unroll
                for (int c = 0; c < 4; ++c) {
                    const short8 bfr = *(const short8*)(&Bs[(16 * c + l16) * 72 + k2 + quad * 8]);
                    acc[c] = __builtin_amdgcn_mfma_f32_16x16x32_bf16(af, bfr, acc[c], 0, 0, 0);
                }
            }
        }
#pragma unroll
        for (int c = 0; c < 4; ++c)
#pragma unroll
            for (int r = 0; r < 4; ++r) {
                const int il = 16 * w + quad * 4 + r;
                const int ol = 16 * c + l16;
                out[((size_t)b * Ss + it * 64 + il) * Hh + ot * 64 + ol] = acc[c][r];
            }
    }
}

extern "C" void kernel_launch(void* const* d_in, const int* in_sizes, int n_in,
                              void* d_out, int out_size, void* d_ws, size_t ws_size,
                              hipStream_t stream) {
    const float* h = (const float*)d_in[0];       // [4,256,768] fp32
    const int* rels = (const int*)d_in[1];        // [4,256,256] i32
    const float* basic = (const float*)d_in[2];   // [4,768,768] fp32
    const float* relw = (const float*)d_in[3];    // [64,4] fp32
    const float* selfw = (const float*)d_in[4];   // [768,768] fp32 (out,in)
    float* out = (float*)d_out;                   // [4,256,768] fp32

    // ws layout (u16 elems, 16B-aligned)
    u16* basicT = (u16*)d_ws;                          // 2,359,296
    u16* coefC = basicT + (size_t)4 * Hh * Hh;         // 1,048,576
    u16* Gt = coefC + (size_t)Bb * 4 * Ss * Ss;        // 3,145,728  [bk][o][j]
    u16* hbf = Gt + (size_t)Bb * 4 * Hh * Ss;          //   786,432
    u16* swbf = hbf + (size_t)Bb * Ss * Hh;            //   589,824
    int* bar = (int*)(swbf + (size_t)Hh * Hh);         // 3 ints (flag + 2 counters)

    k_fused<<<GRID, 256, 0, stream>>>(h, rels, basic, relw, selfw,
                                      basicT, coefC, hbf, swbf, Gt, bar, out);
}

// Round 10
// 148.484 us; speedup vs baseline: 1.3320x; 1.3320x over previous
//
#include <hip/hip_runtime.h>
#include <stdint.h>

typedef unsigned short u16;
typedef unsigned int u32;
typedef __attribute__((ext_vector_type(8))) short short8;
typedef __attribute__((ext_vector_type(4))) float float4v;

#define Bb 4
#define Ss 256
#define Hh 768
#define NALL 64
#define GRID 256          // 1 block/CU: co-resident, and HALF the barrier pollers
#define MAGIC 0x1234ABCD

// Inputs/outputs are FP32 (reference dtype; established r7).

__device__ __forceinline__ float b2f(u16 h) {
    u32 u = ((u32)h) << 16;
    float f;
    __builtin_memcpy(&f, &u, 4);
    return f;
}
__device__ __forceinline__ u16 f2b(float f) {
    u32 u;
    __builtin_memcpy(&u, &f, 4);
    u = (u + 0x7fffu + ((u >> 16) & 1u)) >> 16;  // RNE
    return (u16)u;
}

// Grid barrier. r4 lesson: no acquire in the poll (L2 inv per iteration).
// r9 lesson: poll RATE is the killer — 512 pollers at s_sleep(1) ≈ 19G
// atomic-loads/s onto one LLC line; arrivals queue behind the poll flood
// (congestion collapse, ~60us/barrier). Fix: 256 pollers × s_sleep(32)
// (~0.85us) ≈ 300K polls/s aggregate — negligible; detection adds <1us.
__device__ __forceinline__ void gbar(int* bar, int idx) {
    __syncthreads();
    if (threadIdx.x == 0) {
        while (__hip_atomic_load(&bar[0], __ATOMIC_RELAXED, __HIP_MEMORY_SCOPE_AGENT) != MAGIC)
            __builtin_amdgcn_s_sleep(8);
        __hip_atomic_fetch_add(&bar[1 + idx], 1, __ATOMIC_RELEASE, __HIP_MEMORY_SCOPE_AGENT);
        while (__hip_atomic_load(&bar[1 + idx], __ATOMIC_RELAXED, __HIP_MEMORY_SCOPE_AGENT) < GRID)
            __builtin_amdgcn_s_sleep(32);
        __builtin_amdgcn_fence(__ATOMIC_ACQUIRE, "agent");  // one inv per block, after exit
    }
    __syncthreads();
}

__global__ __launch_bounds__(256, 2) void k_fused(const float* __restrict__ h,
                                                  const int* __restrict__ rels,
                                                  const float* __restrict__ basic,
                                                  const float* __restrict__ relw,
                                                  const float* __restrict__ selfw,
                                                  u16* __restrict__ basicT,
                                                  u16* __restrict__ coefC,
                                                  u16* __restrict__ hbf,
                                                  u16* __restrict__ swbf,
                                                  u16* __restrict__ Gt,
                                                  int* __restrict__ bar,
                                                  float* __restrict__ out) {
    __shared__ __align__(16) u16 As[64 * 72];
    __shared__ __align__(16) u16 Bs[64 * 72];
    const int t = threadIdx.x;
    const int row = t >> 2, kk = (t & 3) * 16;
    const int w = t >> 6, l = t & 63, quad = l >> 4, l16 = l & 15;

    if (blockIdx.x == 0 && t == 0) {
        __hip_atomic_store(&bar[1], 0, __ATOMIC_RELAXED, __HIP_MEMORY_SCOPE_AGENT);
        __hip_atomic_store(&bar[2], 0, __ATOMIC_RELAXED, __HIP_MEMORY_SCOPE_AGENT);
        __hip_atomic_store(&bar[0], MAGIC, __ATOMIC_RELEASE, __HIP_MEMORY_SCOPE_AGENT);
    }

    // -------- phase A (4672 units): basicT | hbf cvt | swbf cvt | coefC --------
    //  [0,2304) basicT transpose  [2304,3072) hbf  [3072,3648) swbf  [3648,4672) coefC
    {
        u16(*tile)[34] = (u16(*)[34])As;  // 32x34 pad: conflict-free transposed read
        float* srelw = (float*)Bs;
        u32* hist = (u32*)(Bs + 1024);
        for (int u = blockIdx.x; u < 4672; u += GRID) {
            __syncthreads();  // protect LDS reuse across units
            if (u < 2304) {   // basicT[q][o][i] = bf16(basic[q][i][o])
                const int q = u / 576, rem = u % 576;
                const int i0 = (rem % 24) * 32, o0 = (rem / 24) * 32;
                const int tx = t & 31, ty = t >> 5;
                const size_t base = (size_t)q * Hh * Hh;
#pragma unroll
                for (int r = 0; r < 4; ++r)
                    tile[ty + 8 * r][tx] =
                        f2b(basic[base + (size_t)(i0 + ty + 8 * r) * Hh + o0 + tx]);
                __syncthreads();
#pragma unroll
                for (int r = 0; r < 4; ++r)
                    basicT[base + (size_t)(o0 + ty + 8 * r) * Hh + i0 + tx] = tile[tx][ty + 8 * r];
            } else if (u < 3072) {   // hbf cvt
                const size_t i = ((size_t)(u - 2304) * 256 + t) * 4;
                const float4 v = *(const float4*)(h + i);
                u32 lo = (u32)f2b(v.x) | ((u32)f2b(v.y) << 16);
                u32 hi = (u32)f2b(v.z) | ((u32)f2b(v.w) << 16);
                *(uint2*)(hbf + i) = make_uint2(lo, hi);
            } else if (u < 3648) {   // swbf cvt
                const size_t i = ((size_t)(u - 3072) * 256 + t) * 4;
                const float4 v = *(const float4*)(selfw + i);
                u32 lo = (u32)f2b(v.x) | ((u32)f2b(v.y) << 16);
                u32 hi = (u32)f2b(v.z) | ((u32)f2b(v.w) << 16);
                *(uint2*)(swbf + i) = make_uint2(lo, hi);
            } else {                 // coefC build: one unit per (b,i)
                const int r = u - 3648;
                const int i = r & 255, b = r >> 8;
                srelw[t] = relw[t];
                if (t < NALL) hist[t] = 0u;
                __syncthreads();
                const int rfw = rels[(b * Ss + i) * Ss + t];
                const int rcl = rels[(b * Ss + t) * Ss + i];
                if (rfw > 0) atomicAdd(&hist[rfw], 1u);
                if (rcl > 0) atomicAdd(&hist[rcl + 32], 1u);
                __syncthreads();
                float c0 = 0.f, c1 = 0.f, c2 = 0.f, c3 = 0.f;
                if (rfw > 0) {
                    const float inv = 1.0f / (float)hist[rfw];
                    c0 += srelw[rfw * 4 + 0] * inv; c1 += srelw[rfw * 4 + 1] * inv;
                    c2 += srelw[rfw * 4 + 2] * inv; c3 += srelw[rfw * 4 + 3] * inv;
                }
                if (rcl > 0) {
                    const int rr = rcl + 32;
                    const float inv = 1.0f / (float)hist[rr];
                    c0 += srelw[rr * 4 + 0] * inv; c1 += srelw[rr * 4 + 1] * inv;
                    c2 += srelw[rr * 4 + 2] * inv; c3 += srelw[rr * 4 + 3] * inv;
                }
                const size_t base = ((size_t)(b * 4) * Ss + i) * Ss + t;
                coefC[base] = f2b(c0);
                coefC[base + (size_t)Ss * Ss] = f2b(c1);
                coefC[base + (size_t)2 * Ss * Ss] = f2b(c2);
                coefC[base + (size_t)3 * Ss * Ss] = f2b(c3);
            }
        }
    }
    gbar(bar, 0);

    // -------- phase B (768 units, exactly 3/block): Gt GEMM --------
    // Gt[bk][o][j] = sum_i basicT[q][o][i] * hbf[b][j][i]; K=768
    for (int u = blockIdx.x; u < 768; u += GRID) {
        const int o0 = (u % 12) * 64, j0 = ((u / 12) % 4) * 64, bk = u / 48;
        const int b = bk >> 2, q = bk & 3;
        const u16* aB = basicT + ((size_t)q * Hh + o0 + row) * Hh + kk;
        const u16* bB = hbf + ((size_t)b * Ss + j0 + row) * Hh + kk;
        float4v acc[4];
#pragma unroll
        for (int c = 0; c < 4; ++c) acc[c] = (float4v){0.f, 0.f, 0.f, 0.f};
        uint4 a0 = *(const uint4*)aB, a1 = *(const uint4*)(aB + 8);
        uint4 b0 = *(const uint4*)bB, b1 = *(const uint4*)(bB + 8);
        for (int s = 0; s < 12; ++s) {
            __syncthreads();
            *(uint4*)(&As[row * 72 + kk]) = a0;
            *(uint4*)(&As[row * 72 + kk + 8]) = a1;
            *(uint4*)(&Bs[row * 72 + kk]) = b0;
            *(uint4*)(&Bs[row * 72 + kk + 8]) = b1;
            __syncthreads();
            if (s + 1 < 12) {
                a0 = *(const uint4*)(aB + (s + 1) * 64);
                a1 = *(const uint4*)(aB + (s + 1) * 64 + 8);
                b0 = *(const uint4*)(bB + (s + 1) * 64);
                b1 = *(const uint4*)(bB + (s + 1) * 64 + 8);
            }
#pragma unroll
            for (int k2 = 0; k2 < 64; k2 += 32) {
                const short8 af = *(const short8*)(&As[(16 * w + l16) * 72 + k2 + quad * 8]);
#pragma unroll
                for (int c = 0; c < 4; ++c) {
                    const short8 bfr = *(const short8*)(&Bs[(16 * c + l16) * 72 + k2 + quad * 8]);
                    acc[c] = __builtin_amdgcn_mfma_f32_16x16x32_bf16(af, bfr, acc[c], 0, 0, 0);
                }
            }
        }
#pragma unroll
        for (int c = 0; c < 4; ++c)
#pragma unroll
            for (int r = 0; r < 4; ++r) {
                const int ol = 16 * w + quad * 4 + r;   // D row = m = o_local
                const int jl = 16 * c + l16;            // D col = n = j_local
                Gt[((size_t)bk * Hh + o0 + ol) * Ss + j0 + jl] = f2b(acc[c][r]);
            }
    }
    gbar(bar, 1);

    // -------- phase C (192 units): out = coefC@Gt (K=1024) ⊕ hbf@swbf^T (K=768) --------
    if (blockIdx.x < 192) {
        const int z = blockIdx.x;
        const int ot = z % 12, it = (z / 12) % 4, b = z / 48;
        auto aa = [&](int s) -> const u16* {
            if (s < 16)
                return coefC + ((size_t)(b * 4 + (s >> 2)) * Ss + it * 64 + row) * Ss + (s & 3) * 64 + kk;
            return hbf + ((size_t)b * Ss + it * 64 + row) * Hh + (s - 16) * 64 + kk;
        };
        auto bb = [&](int s) -> const u16* {
            if (s < 16)
                return Gt + ((size_t)(b * 4 + (s >> 2)) * Hh + ot * 64 + row) * Ss + (s & 3) * 64 + kk;
            return swbf + (size_t)(ot * 64 + row) * Hh + (s - 16) * 64 + kk;
        };
        float4v acc[4];
#pragma unroll
        for (int c = 0; c < 4; ++c) acc[c] = (float4v){0.f, 0.f, 0.f, 0.f};
        uint4 a0 = *(const uint4*)aa(0);
        uint4 a1 = *(const uint4*)(aa(0) + 8);
        uint4 b0 = *(const uint4*)bb(0);
        uint4 b1 = *(const uint4*)(bb(0) + 8);
        for (int s = 0; s < 28; ++s) {
            __syncthreads();
            *(uint4*)(&As[row * 72 + kk]) = a0;
            *(uint4*)(&As[row * 72 + kk + 8]) = a1;
            *(uint4*)(&Bs[row * 72 + kk]) = b0;
            *(uint4*)(&Bs[row * 72 + kk + 8]) = b1;
            __syncthreads();
            if (s + 1 < 28) {
                const u16* ap = aa(s + 1);
                const u16* bp = bb(s + 1);
                a0 = *(const uint4*)ap;
                a1 = *(const uint4*)(ap + 8);
                b0 = *(const uint4*)bp;
                b1 = *(const uint4*)(bp + 8);
            }
#pragma unroll
            for (int k2 = 0; k2 < 64; k2 += 32) {
                const short8 af = *(const short8*)(&As[(16 * w + l16) * 72 + k2 + quad * 8]);
#pragma unroll
                for (int c = 0; c < 4; ++c) {
                    const short8 bfr = *(const short8*)(&Bs[(16 * c + l16) * 72 + k2 + quad * 8]);
                    acc[c] = __builtin_amdgcn_mfma_f32_16x16x32_bf16(af, bfr, acc[c], 0, 0, 0);
                }
            }
        }
#pragma unroll
        for (int c = 0; c < 4; ++c)
#pragma unroll
            for (int r = 0; r < 4; ++r) {
                const int il = 16 * w + quad * 4 + r;
                const int ol = 16 * c + l16;
                out[((size_t)b * Ss + it * 64 + il) * Hh + ot * 64 + ol] = acc[c][r];
            }
    }
}

extern "C" void kernel_launch(void* const* d_in, const int* in_sizes, int n_in,
                              void* d_out, int out_size, void* d_ws, size_t ws_size,
                              hipStream_t stream) {
    const float* h = (const float*)d_in[0];       // [4,256,768] fp32
    const int* rels = (const int*)d_in[1];        // [4,256,256] i32
    const float* basic = (const float*)d_in[2];   // [4,768,768] fp32
    const float* relw = (const float*)d_in[3];    // [64,4] fp32
    const float* selfw = (const float*)d_in[4];   // [768,768] fp32 (out,in)
    float* out = (float*)d_out;                   // [4,256,768] fp32

    // ws layout (u16 elems, 16B-aligned)
    u16* basicT = (u16*)d_ws;                          // 2,359,296
    u16* coefC = basicT + (size_t)4 * Hh * Hh;         // 1,048,576
    u16* Gt = coefC + (size_t)Bb * 4 * Ss * Ss;        // 3,145,728  [bk][o][j]
    u16* hbf = Gt + (size_t)Bb * 4 * Hh * Ss;          //   786,432
    u16* swbf = hbf + (size_t)Bb * Ss * Hh;            //   589,824
    int* bar = (int*)(swbf + (size_t)Hh * Hh);         // 3 ints (flag + 2 counters)

    k_fused<<<GRID, 256, 0, stream>>>(h, rels, basic, relw, selfw,
                                      basicT, coefC, hbf, swbf, Gt, bar, out);
}